// Round 7
// baseline (1415.412 us; speedup 1.0000x reference)
//
#include <hip/hip_runtime.h>
#include <cstdint>
#include <cstddef>

#define B_  64
#define NC_ 32
#define NL_ 64
#define E_  256
#define H_  256

// ---------------- Threefry-2x32, 20 rounds (JAX-compatible) ----------------
__device__ __forceinline__ void tf2x32(unsigned k0, unsigned k1,
                                       unsigned c0, unsigned c1,
                                       unsigned &o0, unsigned &o1) {
  unsigned ks2 = k0 ^ k1 ^ 0x1BD11BDAu;
  unsigned x0 = c0 + k0, x1 = c1 + k1;
#define TFR(r) { x0 += x1; x1 = (x1 << r) | (x1 >> (32 - r)); x1 ^= x0; }
  TFR(13) TFR(15) TFR(26) TFR(6)   x0 += k1;  x1 += ks2 + 1u;
  TFR(17) TFR(29) TFR(16) TFR(24)  x0 += ks2; x1 += k0 + 2u;
  TFR(13) TFR(15) TFR(26) TFR(6)   x0 += k0;  x1 += k1 + 3u;
  TFR(17) TFR(29) TFR(16) TFR(24)  x0 += k1;  x1 += ks2 + 4u;
  TFR(13) TFR(15) TFR(26) TFR(6)   x0 += ks2; x1 += k0 + 5u;
#undef TFR
  o0 = x0; o1 = x1;
}

__device__ __forceinline__ float gumbel_bits(unsigned k0, unsigned k1, unsigned flat) {
  unsigned a, b;
  tf2x32(k0, k1, 0u, flat, a, b);
  unsigned bits = a ^ b;
  float f = __uint_as_float(0x3F800000u | (bits >> 9)) - 1.0f;
  f = fmaxf(f, 1.17549435e-38f);
  return -logf(-logf(f));
}

// tanh via native exp + native rcp (no IEEE divide sequence).
__device__ __forceinline__ float ftanh(float x) {
  float e = __expf(2.0f * x);
  return fmaf(-2.0f, __builtin_amdgcn_rcpf(e + 1.0f), 1.0f);
}

// ---------------- K0: keys + init vectors + sum(lv) ----------------
__global__ __launch_bounds__(256) void k0_kernel(
    const float* __restrict__ init_w, const float* __restrict__ Wv,
    const float* __restrict__ hWq,
    const float* __restrict__ low_init_w, const float* __restrict__ lWv,
    const float* __restrict__ lWq, const float* __restrict__ lvin,
    unsigned* __restrict__ hkeys, unsigned* __restrict__ lkeys,
    float* __restrict__ g0h, float* __restrict__ g0l,
    float* __restrict__ Lsum) {
  int tid = threadIdx.x;
  __shared__ float s_iwv[E_], s_liwv[E_];
  if (tid < 32) {
    unsigned a, b;
    tf2x32(0u, 42u, 0u, (unsigned)tid, a, b);
    hkeys[2*tid] = a; hkeys[2*tid+1] = b;
    tf2x32(0u, 7u, 0u, (unsigned)tid, a, b);
    lkeys[2*tid] = a; lkeys[2*tid+1] = b;
  }
  if (tid == 0) {
    float s = 0.f;
    for (int k = 0; k < 256; ++k) s += lvin[k];
    Lsum[0] = s;
  }
  {
    float a = 0.f, a2 = 0.f;
    for (int k = 0; k < 2*E_; ++k) {
      a  = fmaf(init_w[k],     Wv[(size_t)k*E_ + tid], a);
      a2 = fmaf(low_init_w[k], lWv[(size_t)k*E_ + tid], a2);
    }
    s_iwv[tid] = a; s_liwv[tid] = a2;
  }
  __syncthreads();
  {
    float a = 0.f, a2 = 0.f;
    for (int e = 0; e < E_; ++e) {
      a  = fmaf(s_iwv[e],  hWq[(size_t)e*H_ + tid], a);
      a2 = fmaf(s_liwv[e], lWq[(size_t)e*H_ + tid], a2);
    }
    g0h[tid] = a; g0l[tid] = a2;
  }
}

// ---------------- means over middle dim ----------------
__global__ __launch_bounds__(256) void k_mean(const float* __restrict__ in,
                                              float* __restrict__ out, int G) {
  int row = blockIdx.x, h = threadIdx.x;
  const float* p = in + (size_t)row * G * E_ + h;
  float a = 0.f;
  for (int g = 0; g < G; ++g) a += p[(size_t)g * E_];
  out[(size_t)row * E_ + h] = a * (1.0f / G);
}

// ---------------- generic small GEMM: C = (A .+ avec) @ W + bias ----------------
__global__ __launch_bounds__(256) void k_gemm(
    const float* __restrict__ A, int lda, const float* __restrict__ avec,
    const float* __restrict__ W, const float* __restrict__ bias,
    float* __restrict__ C, int M, int N, int K) {
  __shared__ float As[16][17];
  int i0 = blockIdx.x * 16, j0 = blockIdx.y * 64;
  int tx = threadIdx.x & 63, ty = threadIdx.x >> 6;
  int j = j0 + tx;
  float acc[4] = {0.f, 0.f, 0.f, 0.f};
  for (int kk = 0; kk < K; kk += 16) {
    int r = threadIdx.x >> 4, cc = threadIdx.x & 15;
    float av = A[(size_t)(i0 + r) * lda + kk + cc];
    if (avec) av += avec[kk + cc];
    As[r][cc] = av;
    __syncthreads();
#pragma unroll
    for (int kt = 0; kt < 16; ++kt) {
      float w = W[(size_t)(kk + kt) * N + j];
#pragma unroll
      for (int k2 = 0; k2 < 4; ++k2)
        acc[k2] = fmaf(As[ty*4 + k2][kt], w, acc[k2]);
    }
    __syncthreads();
  }
  float bb = bias ? bias[j] : 0.f;
#pragma unroll
  for (int k2 = 0; k2 < 4; ++k2)
    C[(size_t)(i0 + ty*4 + k2) * N + j] = acc[k2] + bb;
}

// ---------------- gathered GEMM: sbase[o] = hq0l[cell_o] + node_ctx[arow_o] @ M1l ----------------
__global__ __launch_bounds__(256) void k_gemmg(
    const float* __restrict__ nodectx, const int* __restrict__ arow,
    const int* __restrict__ cellarr, const float* __restrict__ W,
    const float* __restrict__ hq0l, float* __restrict__ C) {
  __shared__ float As[16][17];
  __shared__ int rows[16];
  int i0 = blockIdx.x * 16, j0 = blockIdx.y * 64;
  int tx = threadIdx.x & 63, ty = threadIdx.x >> 6;
  int j = j0 + tx;
  if (threadIdx.x < 16) rows[threadIdx.x] = arow[i0 + threadIdx.x];
  __syncthreads();
  float acc[4] = {0.f, 0.f, 0.f, 0.f};
  for (int kk = 0; kk < 256; kk += 16) {
    int r = threadIdx.x >> 4, cc = threadIdx.x & 15;
    As[r][cc] = nodectx[(size_t)rows[r] * 256 + kk + cc];
    __syncthreads();
#pragma unroll
    for (int kt = 0; kt < 16; ++kt) {
      float w = W[(size_t)(kk + kt) * 256 + j];
#pragma unroll
      for (int k2 = 0; k2 < 4; ++k2)
        acc[k2] = fmaf(As[ty*4 + k2][kt], w, acc[k2]);
    }
    __syncthreads();
  }
#pragma unroll
  for (int k2 = 0; k2 < 4; ++k2) {
    int row = i0 + ty*4 + k2;
    C[(size_t)row * 256 + j] = acc[k2] + hq0l[(size_t)cellarr[row] * 256 + j];
  }
}

// ---------------- big GEMM v5: [R|Q] = node_ctx(131072x256) @ [lWr | Al](256x512)
// v3 (386 us; BK=16, grid (1024,4), bounds (256,2), 2-way Ws mapping — the
// verified best) + ONE isolated change: double-buffered LDS with
// issue-early / write-late staging (T14). R6 refuted the barrier-COUNT model
// (drain time is per-byte, not per-barrier); the fix is overlap: issue tile
// k+1's global loads BEFORE compute of tile k, ds_write AFTER — the vmcnt
// wait at the write finds data already landed. One barrier per kc-step.
// Inner structure bit-exact-verified in R2 (absmax=0); R2's regression
// correlated with its grid-order change, NOT this structure (R6 exonerated
// the 33.8 KB LDS footprint). K-order per output unchanged -> bitwise R/Q.
__global__ __launch_bounds__(256, 2) void k_bgemm(
    const float* __restrict__ A, const float* __restrict__ Wr,
    const float* __restrict__ Alm, const float* __restrict__ lbr,
    float* __restrict__ Rout, float* __restrict__ Qout) {
  __shared__ float As[2][16][132];
  __shared__ float Ws[2][16][132];
  int bx = blockIdx.x, by = blockIdx.y;
  const float* Wbase = (by < 2) ? Wr : Alm;
  float* Cbase = (by < 2) ? Rout : Qout;
  int jb = (by & 1) * 128;
  bool doBias = (by < 2);
  int m0 = bx * 128;
  int tid = threadIdx.x;
  int tx = tid & 15, ty = tid >> 4;
  int kq = (tid & 3) * 4, ma = tid >> 2;     // A staging coords (v3)
  int kw = tid >> 4, c4 = (tid & 15) * 8;    // W staging coords (v3)
  float acc[8][8];
#pragma unroll
  for (int i = 0; i < 8; ++i)
#pragma unroll
    for (int j = 0; j < 8; ++j) acc[i][j] = 0.f;

  float4 a0, a1, w0, w1;
  // prologue: stage kc=0 into buffer 0
  a0 = *(const float4*)&A[(size_t)(m0 + ma) * 256 + kq];
  a1 = *(const float4*)&A[(size_t)(m0 + ma + 64) * 256 + kq];
  w0 = *(const float4*)&Wbase[(size_t)kw * 256 + jb + c4];
  w1 = *(const float4*)&Wbase[(size_t)kw * 256 + jb + c4 + 4];
  As[0][kq+0][ma] = a0.x; As[0][kq+1][ma] = a0.y;
  As[0][kq+2][ma] = a0.z; As[0][kq+3][ma] = a0.w;
  As[0][kq+0][ma+64] = a1.x; As[0][kq+1][ma+64] = a1.y;
  As[0][kq+2][ma+64] = a1.z; As[0][kq+3][ma+64] = a1.w;
  *(float4*)&Ws[0][kw][c4]     = w0;
  *(float4*)&Ws[0][kw][c4 + 4] = w1;
  __syncthreads();

  for (int kc = 0; kc < 256; kc += 16) {
    int cur = (kc >> 4) & 1;
    bool more = (kc + 16) < 256;
    if (more) {  // issue next tile's loads early; land during compute below
      a0 = *(const float4*)&A[(size_t)(m0 + ma) * 256 + kc + 16 + kq];
      a1 = *(const float4*)&A[(size_t)(m0 + ma + 64) * 256 + kc + 16 + kq];
      w0 = *(const float4*)&Wbase[(size_t)(kc + 16 + kw) * 256 + jb + c4];
      w1 = *(const float4*)&Wbase[(size_t)(kc + 16 + kw) * 256 + jb + c4 + 4];
    }
    const float (*Asb)[132] = As[cur];
    const float (*Wsb)[132] = Ws[cur];
#pragma unroll
    for (int k = 0; k < 16; ++k) {
      float4 va0 = *(const float4*)&Asb[k][ty * 8];
      float4 va1 = *(const float4*)&Asb[k][ty * 8 + 4];
      float4 vw0 = *(const float4*)&Wsb[k][tx * 4];        // 2-way banks (v3)
      float4 vw1 = *(const float4*)&Wsb[k][tx * 4 + 64];
      float av[8] = {va0.x, va0.y, va0.z, va0.w, va1.x, va1.y, va1.z, va1.w};
      float wv[8] = {vw0.x, vw0.y, vw0.z, vw0.w, vw1.x, vw1.y, vw1.z, vw1.w};
#pragma unroll
      for (int i = 0; i < 8; ++i)
#pragma unroll
        for (int j = 0; j < 8; ++j)
          acc[i][j] = fmaf(av[i], wv[j], acc[i][j]);
    }
    if (more) {  // write-late: vmcnt wait here, after compute hid the latency
      int nb = cur ^ 1;
      As[nb][kq+0][ma] = a0.x; As[nb][kq+1][ma] = a0.y;
      As[nb][kq+2][ma] = a0.z; As[nb][kq+3][ma] = a0.w;
      As[nb][kq+0][ma+64] = a1.x; As[nb][kq+1][ma+64] = a1.y;
      As[nb][kq+2][ma+64] = a1.z; As[nb][kq+3][ma+64] = a1.w;
      *(float4*)&Ws[nb][kw][c4]     = w0;
      *(float4*)&Ws[nb][kw][c4 + 4] = w1;
      __syncthreads();
    }
  }
  float bias0[4], bias1[4];
#pragma unroll
  for (int j = 0; j < 4; ++j) {
    bias0[j] = doBias ? lbr[jb + tx * 4 + j] : 0.f;
    bias1[j] = doBias ? lbr[jb + 64 + tx * 4 + j] : 0.f;
  }
#pragma unroll
  for (int i = 0; i < 8; ++i) {
    float4 o0 = make_float4(acc[i][0] + bias0[0], acc[i][1] + bias0[1],
                            acc[i][2] + bias0[2], acc[i][3] + bias0[3]);
    float4 o1 = make_float4(acc[i][4] + bias1[0], acc[i][5] + bias1[1],
                            acc[i][6] + bias1[2], acc[i][7] + bias1[3]);
    size_t row = (size_t)(m0 + ty * 8 + i);
    *(float4*)&Cbase[row * 256 + jb + tx * 4] = o0;
    *(float4*)&Cbase[row * 256 + jb + 64 + tx * 4] = o1;
  }
}

// ---------------- u0 for all cells ----------------
__global__ __launch_bounds__(256) void k_u0k(
    const float* __restrict__ R, const float* __restrict__ hq0l,
    const float* __restrict__ g0l, const float* __restrict__ lv,
    float* __restrict__ u0) {
  int cell = blockIdx.x, tid = threadIdx.x, lane = tid & 63, w = tid >> 6;
  __shared__ float qs[256];
  qs[tid] = hq0l[(size_t)cell*256 + tid] + g0l[tid];
  __syncthreads();
  float lvr[4], qsr[4];
#pragma unroll
  for (int q = 0; q < 4; ++q) { lvr[q] = lv[lane + 64*q]; qsr[q] = qs[lane + 64*q]; }
  const float* Rb = R + (size_t)cell * 16384;
  for (int i = 0; i < 16; ++i) {
    int n = w*16 + i;
    const float* rr = Rb + (size_t)n*256;
    float a = 0.f;
#pragma unroll
    for (int q = 0; q < 4; ++q)
      a = fmaf(lvr[q], ftanh(qsr[q] + rr[lane + 64*q]), a);
#pragma unroll
    for (int off = 32; off; off >>= 1) a += __shfl_xor(a, off);
    if (lane == 0) u0[(size_t)cell*64 + n] = 10.0f * ftanh(a);
  }
}

// ---------------- phase A: high-level sampling chain ----------------
__global__ __launch_bounds__(256) void k_high(
    const float* __restrict__ cell_ctx, const int* __restrict__ high_mask,
    const float* __restrict__ hv,
    const float* __restrict__ ws_hq0h, const float* __restrict__ ws_g0h,
    const float* __restrict__ ws_Qh, const float* __restrict__ ws_rhigh,
    const float* __restrict__ ws_M1h, const unsigned* __restrict__ ws_hkeys,
    int* __restrict__ ws_hidx, float* __restrict__ ws_hlogp) {
  int b = blockIdx.x, tid = threadIdx.x;
  int lane = tid & 63, w = tid >> 6;
  __shared__ float s[H_], addM[H_], hq0[H_], g0[H_], hvv[H_];
  __shared__ float uarr[NC_];
  __shared__ int prev_s;
  __shared__ unsigned hm_s;
  __shared__ float acc_s;
  hq0[tid] = ws_hq0h[(size_t)b*H_ + tid];
  g0[tid] = ws_g0h[tid];
  hvv[tid] = hv[tid];
  if (tid == 0) {
    unsigned m = 0;
    for (int c = 0; c < NC_; ++c) if (high_mask[b*NC_ + c] > 0) m |= (1u << c);
    hm_s = m; acc_s = 0.f; prev_s = 0;
  }
  __syncthreads();
  for (int t = 0; t < NC_; ++t) {
    {
      float v = hq0[tid];
      if (t == 0) v += g0[tid];
      else        v += addM[tid] + ws_Qh[(size_t)(b*NC_ + prev_s)*H_ + tid];
      s[tid] = v;
    }
    __syncthreads();
    unsigned hm = hm_s;
    for (int q8 = 0; q8 < 8; ++q8) {
      int cidx = w*8 + q8;
      if ((hm >> cidx) & 1u) continue;
      const float* rr = ws_rhigh + (size_t)(b*NC_ + cidx)*H_;
      float a = 0.f;
#pragma unroll
      for (int jj = 0; jj < 4; ++jj) {
        int h = lane + 64*jj;
        a += hvv[h] * ftanh(s[h] + rr[h]);
      }
#pragma unroll
      for (int off = 32; off; off >>= 1) a += __shfl_xor(a, off);
      if (lane == 0) uarr[cidx] = 10.0f * ftanh(a);
    }
    __syncthreads();
    if (w == 0) {
      int cidx = lane;
      bool valid = (cidx < NC_);
      bool masked = valid && ((hm >> cidx) & 1u);
      float logit = valid ? (masked ? -1e9f : uarr[cidx]) : -INFINITY;
      float val = -INFINITY;
      if (valid) {
        float g = gumbel_bits(ws_hkeys[2*t], ws_hkeys[2*t+1],
                              (unsigned)(b*NC_ + cidx));
        val = logit + g;
      }
      float bvv = val; int bi = valid ? cidx : 9999;
#pragma unroll
      for (int off = 32; off; off >>= 1) {
        float ov = __shfl_xor(bvv, off); int oi = __shfl_xor(bi, off);
        if (ov > bvv || (ov == bvv && oi < bi)) { bvv = ov; bi = oi; }
      }
      float m = logit;
#pragma unroll
      for (int off = 32; off; off >>= 1) m = fmaxf(m, __shfl_xor(m, off));
      float ex = (valid && !masked) ? expf(logit - m) : 0.f;
#pragma unroll
      for (int off = 32; off; off >>= 1) ex += __shfl_xor(ex, off);
      float lsel = __shfl(logit, bi);
      float logp = lsel - m - logf(ex);
      if (lane == 0) {
        acc_s += logp;
        ws_hidx[b*NC_ + t] = bi;
        hm_s = hm | (1u << bi);
        prev_s = bi;
      }
    }
    __syncthreads();
    if (t == 0) {
      {
        int idx0 = prev_s;
        const float* crow = cell_ctx + (size_t)(b*NC_ + idx0)*E_;
        float a = 0.f;
        for (int e = 0; e < E_; ++e)
          a = fmaf(crow[e], ws_M1h[(size_t)e*H_ + tid], a);
        addM[tid] = a;
      }
      __syncthreads();
    }
  }
  if (tid == 0) ws_hlogp[b] = acc_s;
}

// ---------------- idx0 sampling (step 0) per (b,t) ----------------
__global__ __launch_bounds__(256) void k_idx0(
    const int* __restrict__ low_mask, const unsigned* __restrict__ lkeys,
    const int* __restrict__ hidx, const float* __restrict__ u0,
    int* __restrict__ arow, int* __restrict__ cellarr) {
  int tid = threadIdx.x, lane = tid & 63, w = tid >> 6;
  int o = blockIdx.x * 4 + w;
  int b = o >> 5, t = o & 31;
  int c = hidx[o], cell = b*NC_ + c;
  float logit = (low_mask[(size_t)cell*64 + lane] > 0) ? -1e9f
               : u0[(size_t)cell*64 + lane];
  unsigned s0, s1;
  tf2x32(lkeys[2*t], lkeys[2*t+1], 0u, 0u, s0, s1);
  float g = gumbel_bits(s0, s1, (unsigned)(b*NL_ + lane));
  float val = logit + g;
  float bvv = val; int bi = lane;
#pragma unroll
  for (int off = 32; off; off >>= 1) {
    float ov = __shfl_xor(bvv, off); int oi = __shfl_xor(bi, off);
    if (ov > bvv || (ov == bvv && oi < bi)) { bvv = ov; bi = oi; }
  }
  if (lane == 0) { arow[o] = cell*64 + bi; cellarr[o] = cell; }
}

// ---------------- U table v4: separable exp ----------------
// Key identity: exp(2(q+r)) = exp(2q)*exp(2r). Stage Er = exp(2R) into r_lds
// (16K exps/block) and Eq = exp(2(sb+Q)) into qrow (32K exps/block) instead of
// applying exp per (j,n,h) element (1.05M exps/block). Inner element:
//   acc = fma(lv, rcp(fma(Eq, Er, 1.0)), acc)
#define S_LDS 260
#define QPAD  264
__global__ __launch_bounds__(512, 6) void k_utab(
    const float* __restrict__ R, const float* __restrict__ Qm,
    const float* __restrict__ sbase, const float* __restrict__ lv,
    const float* __restrict__ Lsum, const int* __restrict__ hidx,
    float* __restrict__ U) {
  __shared__ float r_lds[32 * S_LDS];     // 32 rows of exp(2*r)  (33.3 KB)
  __shared__ float qrow[8][2 * QPAD];     // per-wave exp(2*(sbase+Q[j0/j1])) (16.9 KB)
  __shared__ float lvs[256];
  int tid = threadIdx.x, lane = tid & 63, w = tid >> 6;
  int o = blockIdx.x;
  int c = hidx[o], cell = (o >> 5) * NC_ + c;
  const float* Rb = R + (size_t)cell * 16384;
  const float* Qb = Qm + (size_t)cell * 16384;
  if (tid < 64) *(float4*)&lvs[4*tid] = *(const float4*)&lv[4*tid];
  float Ls = Lsum[0];
  float4 sb4 = *(const float4*)&sbase[(size_t)o*256 + 4*lane];
  int rbase = (lane >> 5) * 128;   // h-half this lane covers
  int nloc = lane & 31;            // local row index (conflict-free: measured r3)
  float* qw = qrow[w];
  for (int p = 0; p < 2; ++p) {
    if (p) __syncthreads();
    // stage rows p*32..+31 as exp(2*r), fully coalesced
#pragma unroll
    for (int k = 0; k < 4; ++k) {
      int f = tid + 512*k;
      int nl = f >> 6, h4 = (f & 63) * 4;
      float4 v = *(const float4*)&Rb[(size_t)(p*32 + nl)*256 + h4];
      *(float4*)&r_lds[nl*S_LDS + h4] =
          make_float4(__expf(v.x + v.x), __expf(v.y + v.y),
                      __expf(v.z + v.z), __expf(v.w + v.w));
    }
    __syncthreads();
    for (int jj = 0; jj < 4; ++jj) {
      int j0 = w*8 + 2*jj;
      {
        float4 qa = *(const float4*)&Qb[(size_t)j0*256 + 4*lane];
        float4 qb = *(const float4*)&Qb[(size_t)(j0+1)*256 + 4*lane];
        *(float4*)&qw[4*lane] =
            make_float4(__expf(2.f*(sb4.x + qa.x)), __expf(2.f*(sb4.y + qa.y)),
                        __expf(2.f*(sb4.z + qa.z)), __expf(2.f*(sb4.w + qa.w)));
        *(float4*)&qw[QPAD + 4*lane] =
            make_float4(__expf(2.f*(sb4.x + qb.x)), __expf(2.f*(sb4.y + qb.y)),
                        __expf(2.f*(sb4.z + qb.z)), __expf(2.f*(sb4.w + qb.w)));
      }
      // in-wave LDS RAW on qw: per-wave DS ordering (r3-proven pattern)
      float4 acc0 = make_float4(0.f, 0.f, 0.f, 0.f);
      float4 acc1 = make_float4(0.f, 0.f, 0.f, 0.f);
#pragma unroll 8
      for (int cc = 0; cc < 32; ++cc) {
        int hh = rbase + 4*cc;
        float4 rv = *(float4*)&r_lds[nloc*S_LDS + hh];   // Er
        float4 l4 = *(float4*)&lvs[hh];
        float4 q0 = *(float4*)&qw[hh];                   // Eq (j0)
        float4 q1 = *(float4*)&qw[QPAD + hh];            // Eq (j0+1)
        acc0.x = fmaf(l4.x, __builtin_amdgcn_rcpf(fmaf(q0.x, rv.x, 1.f)), acc0.x);
        acc0.y = fmaf(l4.y, __builtin_amdgcn_rcpf(fmaf(q0.y, rv.y, 1.f)), acc0.y);
        acc0.z = fmaf(l4.z, __builtin_amdgcn_rcpf(fmaf(q0.z, rv.z, 1.f)), acc0.z);
        acc0.w = fmaf(l4.w, __builtin_amdgcn_rcpf(fmaf(q0.w, rv.w, 1.f)), acc0.w);
        acc1.x = fmaf(l4.x, __builtin_amdgcn_rcpf(fmaf(q1.x, rv.x, 1.f)), acc1.x);
        acc1.y = fmaf(l4.y, __builtin_amdgcn_rcpf(fmaf(q1.y, rv.y, 1.f)), acc1.y);
        acc1.z = fmaf(l4.z, __builtin_amdgcn_rcpf(fmaf(q1.z, rv.z, 1.f)), acc1.z);
        acc1.w = fmaf(l4.w, __builtin_amdgcn_rcpf(fmaf(q1.w, rv.w, 1.f)), acc1.w);
      }
      // u = 10*tanh(L - 2*S) where S = sum lv*sigma(-2z)
      float a0 = (acc0.x + acc0.y) + (acc0.z + acc0.w);
      float a1 = (acc1.x + acc1.y) + (acc1.z + acc1.w);
      a0 += __shfl_xor(a0, 32);
      a1 += __shfl_xor(a1, 32);
      if (lane < 32) {
        float* Uo = U + (size_t)o*4096 + j0*64 + p*32 + lane;
        Uo[0]  = 10.0f * ftanh(fmaf(-2.f, a0, Ls));
        Uo[64] = 10.0f * ftanh(fmaf(-2.f, a1, Ls));
      }
    }
  }
}

// ---------------- sequential low sampler: one wave per (b,t) ----------------
__global__ __launch_bounds__(256) void k_lowseq(
    const float* __restrict__ orig, const int* __restrict__ low_mask,
    const unsigned* __restrict__ lkeys, const int* __restrict__ hidx,
    const float* __restrict__ u0, const float* __restrict__ U,
    float* __restrict__ llogp, float* __restrict__ lRr,
    float* __restrict__ lastn, float* __restrict__ initn) {
  int tid = threadIdx.x, lane = tid & 63, w = tid >> 6;
  int o = blockIdx.x * 4 + w;
  int b = o >> 5, t = o & 31;
  int c = hidx[o], cell = b*NC_ + c;
  float cx = orig[(size_t)cell*128 + 2*lane];
  float cy = orig[(size_t)cell*128 + 2*lane + 1];
  int maskb = (low_mask[(size_t)cell*64 + lane] > 0) ? 1 : 0;
  unsigned sk0, sk1;
  tf2x32(lkeys[2*t], lkeys[2*t+1], 0u, (unsigned)lane, sk0, sk1);
  float row = u0[(size_t)cell*64 + lane];
  float px = __shfl(cx, 0), py = __shfl(cy, 0);
  float ix = px, iy = py;
  float lp = 0.f, rw = 0.f;
  const float* Ub = U + (size_t)o * 4096;
  for (int s = 0; s < NL_; ++s) {
    float logit = maskb ? -1e9f : row;
    unsigned k0 = (unsigned)__shfl((int)sk0, s);
    unsigned k1 = (unsigned)__shfl((int)sk1, s);
    float g = gumbel_bits(k0, k1, (unsigned)(b*NL_ + lane));
    float val = logit + g;
    float bvv = val; int bi = lane;
#pragma unroll
    for (int off = 32; off; off >>= 1) {
      float ov = __shfl_xor(bvv, off); int oi = __shfl_xor(bi, off);
      if (ov > bvv || (ov == bvv && oi < bi)) { bvv = ov; bi = oi; }
    }
    float nrow = Ub[(size_t)bi*64 + lane];
    float m = logit;
#pragma unroll
    for (int off = 32; off; off >>= 1) m = fmaxf(m, __shfl_xor(m, off));
    float ex = maskb ? 0.f : expf(logit - m);
#pragma unroll
    for (int off = 32; off; off >>= 1) ex += __shfl_xor(ex, off);
    float lsel = __shfl(logit, bi);
    lp += lsel - m - logf(ex);
    float bx = __shfl(cx, bi), by = __shfl(cy, bi);
    float dx = bx - px, dy = by - py;
    rw += sqrtf(dx*dx + dy*dy + 1e-12f);
    px = bx; py = by;
    if (lane == bi) maskb = 1;
    row = nrow;
  }
  if (lane == 0) {
    llogp[o] = lp; lRr[o] = rw;
    lastn[2*o] = px; lastn[2*o+1] = py;
    initn[2*o] = ix; initn[2*o+1] = iy;
  }
}

// ---------------- phase C: stitch ----------------
__global__ __launch_bounds__(64) void k_stitch(
    const float* __restrict__ ws_hlogp, const float* __restrict__ ws_llogp,
    const float* __restrict__ ws_lR, const float* __restrict__ ws_lastn,
    const float* __restrict__ ws_initn, float* __restrict__ out) {
  int b = threadIdx.x;
  if (b >= B_) return;
  float lp = ws_hlogp[b], rw = 0.f, lx = 0.f, ly = 0.f;
  for (int t = 0; t < NC_; ++t) {
    int o = b*NC_ + t;
    lp += ws_llogp[o];
    float dx = ws_initn[2*o] - lx, dy = ws_initn[2*o+1] - ly;
    rw += ws_lR[o] + sqrtf(dx*dx + dy*dy + 1e-12f);
    lx = ws_lastn[2*o]; ly = ws_lastn[2*o+1];
  }
  out[b] = lp;
  out[B_ + b] = rw;
}

// ---------------- host launcher ----------------
extern "C" void kernel_launch(void* const* d_in, const int* in_sizes, int n_in,
                              void* d_out, int out_size, void* d_ws, size_t ws_size,
                              hipStream_t stream) {
  const float* node_ctx  = (const float*)d_in[0];
  const float* cell_ctx  = (const float*)d_in[1];
  const float* orig      = (const float*)d_in[2];
  const int*   high_mask = (const int*)d_in[3];
  const int*   low_mask  = (const int*)d_in[4];
  const float* init_w    = (const float*)d_in[5];
  const float* Wc        = (const float*)d_in[6];
  const float* bc        = (const float*)d_in[7];
  const float* Wv        = (const float*)d_in[8];
  const float* bv        = (const float*)d_in[9];
  const float* hWq       = (const float*)d_in[10];
  const float* hbq       = (const float*)d_in[11];
  const float* hWr       = (const float*)d_in[12];
  const float* hbr       = (const float*)d_in[13];
  const float* hv        = (const float*)d_in[14];
  const float* low_init_w= (const float*)d_in[15];
  const float* lWc       = (const float*)d_in[16];
  const float* lbc       = (const float*)d_in[17];
  const float* lWv       = (const float*)d_in[18];
  const float* lbv       = (const float*)d_in[19];
  const float* lWq       = (const float*)d_in[20];
  const float* lbq       = (const float*)d_in[21];
  const float* lWr       = (const float*)d_in[22];
  const float* lbr       = (const float*)d_in[23];
  const float* lv        = (const float*)d_in[24];
  float* out = (float*)d_out;

  char* ws = (char*)d_ws;
  size_t off = 0;
  auto alloc = [&](size_t bytes) -> void* {
    void* p = ws + off;
    off += (bytes + 255) & ~(size_t)255;
    return p;
  };
  unsigned* w_hkeys = (unsigned*)alloc(32*2*4);
  unsigned* w_lkeys = (unsigned*)alloc(32*2*4);
  int*   w_hidx  = (int*)alloc(2048*4);
  int*   w_arow  = (int*)alloc(2048*4);
  int*   w_cell  = (int*)alloc(2048*4);
  float* w_hlogp = (float*)alloc(64*4);
  float* w_llogp = (float*)alloc(2048*4);
  float* w_lR    = (float*)alloc(2048*4);
  float* w_lastn = (float*)alloc(2048*2*4);
  float* w_initn = (float*)alloc(2048*2*4);
  float* w_g0h   = (float*)alloc(256*4);
  float* w_g0l   = (float*)alloc(256*4);
  float* w_Lsum  = (float*)alloc(4);
  float* w_M1h   = (float*)alloc((size_t)65536*4);
  float* w_Ah    = (float*)alloc((size_t)65536*4);
  float* w_M1l   = (float*)alloc((size_t)65536*4);
  float* w_Al    = (float*)alloc((size_t)65536*4);
  float* w_mcc   = (float*)alloc((size_t)64*256*4);
  float* w_mnc   = (float*)alloc((size_t)2048*256*4);
  float* w_hbh   = (float*)alloc((size_t)64*256*4);
  float* w_hq0h  = (float*)alloc((size_t)64*256*4);
  float* w_rhigh = (float*)alloc((size_t)2048*256*4);
  float* w_Qh    = (float*)alloc((size_t)2048*256*4);
  float* w_hbl   = (float*)alloc((size_t)2048*256*4);
  float* w_hq0l  = (float*)alloc((size_t)2048*256*4);
  float* w_u0    = (float*)alloc((size_t)2048*64*4);
  float* w_sbase = (float*)alloc((size_t)2048*256*4);
  float* w_U     = (float*)alloc((size_t)2048*4096*4);
  float* w_R     = (float*)alloc((size_t)2048*64*256*4);
  float* w_Qm    = (float*)alloc((size_t)2048*64*256*4);
  (void)ws_size; (void)in_sizes; (void)n_in; (void)out_size;

  k0_kernel<<<1, 256, 0, stream>>>(init_w, Wv, hWq, low_init_w, lWv, lWq, lv,
                                   w_hkeys, w_lkeys, w_g0h, w_g0l, w_Lsum);
  k_mean<<<2048, 256, 0, stream>>>(node_ctx, w_mnc, 64);
  k_mean<<<64, 256, 0, stream>>>(cell_ctx, w_mcc, 32);

  dim3 g256(16, 4), g2048(128, 4), g64(4, 4);
  k_gemm<<<g256, 256, 0, stream>>>(Wv,            256, nullptr, hWq, nullptr, w_M1h, 256, 256, 256);
  k_gemm<<<g256, 256, 0, stream>>>(Wv + 65536,    256, nullptr, hWq, nullptr, w_Ah,  256, 256, 256);
  k_gemm<<<g256, 256, 0, stream>>>(lWv,           256, nullptr, lWq, nullptr, w_M1l, 256, 256, 256);
  k_gemm<<<g256, 256, 0, stream>>>(lWv + 65536,   256, nullptr, lWq, nullptr, w_Al,  256, 256, 256);
  k_gemm<<<g2048, 256, 0, stream>>>(cell_ctx, 256, nullptr, hWr, hbr, w_rhigh, 2048, 256, 256);
  k_gemm<<<g2048, 256, 0, stream>>>(cell_ctx, 256, nullptr, w_Ah, nullptr, w_Qh, 2048, 256, 256);
  k_gemm<<<g64,   256, 0, stream>>>(w_mcc, 256, nullptr, Wc,  bc,  w_hbh, 64,   256, 256);
  k_gemm<<<g2048, 256, 0, stream>>>(w_mnc, 256, nullptr, lWc, lbc, w_hbl, 2048, 256, 256);
  k_gemm<<<g64,   256, 0, stream>>>(w_hbh, 256, bv,  hWq, hbq, w_hq0h, 64,   256, 256);
  k_gemm<<<g2048, 256, 0, stream>>>(w_hbl, 256, lbv, lWq, lbq, w_hq0l, 2048, 256, 256);

  k_bgemm<<<dim3(1024, 4), 256, 0, stream>>>(node_ctx, lWr, w_Al, lbr, w_R, w_Qm);
  k_u0k<<<2048, 256, 0, stream>>>(w_R, w_hq0l, w_g0l, lv, w_u0);

  k_high<<<64, 256, 0, stream>>>(cell_ctx, high_mask, hv, w_hq0h, w_g0h, w_Qh,
                                 w_rhigh, w_M1h, w_hkeys, w_hidx, w_hlogp);
  k_idx0<<<512, 256, 0, stream>>>(low_mask, w_lkeys, w_hidx, w_u0, w_arow, w_cell);
  k_gemmg<<<dim3(128, 4), 256, 0, stream>>>(node_ctx, w_arow, w_cell, w_M1l,
                                            w_hq0l, w_sbase);
  k_utab<<<2048, 512, 0, stream>>>(w_R, w_Qm, w_sbase, lv, w_Lsum, w_hidx, w_U);
  k_lowseq<<<512, 256, 0, stream>>>(orig, low_mask, w_lkeys, w_hidx, w_u0, w_U,
                                    w_llogp, w_lR, w_lastn, w_initn);
  k_stitch<<<1, 64, 0, stream>>>(w_hlogp, w_llogp, w_lR, w_lastn, w_initn, out);
}

// Round 8
// 1361.728 us; speedup vs baseline: 1.0394x; 1.0394x over previous
//
#include <hip/hip_runtime.h>
#include <cstdint>
#include <cstddef>

#define B_  64
#define NC_ 32
#define NL_ 64
#define E_  256
#define H_  256

// ---------------- Threefry-2x32, 20 rounds (JAX-compatible) ----------------
__device__ __forceinline__ void tf2x32(unsigned k0, unsigned k1,
                                       unsigned c0, unsigned c1,
                                       unsigned &o0, unsigned &o1) {
  unsigned ks2 = k0 ^ k1 ^ 0x1BD11BDAu;
  unsigned x0 = c0 + k0, x1 = c1 + k1;
#define TFR(r) { x0 += x1; x1 = (x1 << r) | (x1 >> (32 - r)); x1 ^= x0; }
  TFR(13) TFR(15) TFR(26) TFR(6)   x0 += k1;  x1 += ks2 + 1u;
  TFR(17) TFR(29) TFR(16) TFR(24)  x0 += ks2; x1 += k0 + 2u;
  TFR(13) TFR(15) TFR(26) TFR(6)   x0 += k0;  x1 += k1 + 3u;
  TFR(17) TFR(29) TFR(16) TFR(24)  x0 += k1;  x1 += ks2 + 4u;
  TFR(13) TFR(15) TFR(26) TFR(6)   x0 += ks2; x1 += k0 + 5u;
#undef TFR
  o0 = x0; o1 = x1;
}

__device__ __forceinline__ float gumbel_bits(unsigned k0, unsigned k1, unsigned flat) {
  unsigned a, b;
  tf2x32(k0, k1, 0u, flat, a, b);
  unsigned bits = a ^ b;
  float f = __uint_as_float(0x3F800000u | (bits >> 9)) - 1.0f;
  f = fmaxf(f, 1.17549435e-38f);
  return -logf(-logf(f));
}

// tanh via native exp + native rcp (no IEEE divide sequence).
__device__ __forceinline__ float ftanh(float x) {
  float e = __expf(2.0f * x);
  return fmaf(-2.0f, __builtin_amdgcn_rcpf(e + 1.0f), 1.0f);
}

// ---------------- K0: keys + init vectors + sum(lv) ----------------
__global__ __launch_bounds__(256) void k0_kernel(
    const float* __restrict__ init_w, const float* __restrict__ Wv,
    const float* __restrict__ hWq,
    const float* __restrict__ low_init_w, const float* __restrict__ lWv,
    const float* __restrict__ lWq, const float* __restrict__ lvin,
    unsigned* __restrict__ hkeys, unsigned* __restrict__ lkeys,
    float* __restrict__ g0h, float* __restrict__ g0l,
    float* __restrict__ Lsum) {
  int tid = threadIdx.x;
  __shared__ float s_iwv[E_], s_liwv[E_];
  if (tid < 32) {
    unsigned a, b;
    tf2x32(0u, 42u, 0u, (unsigned)tid, a, b);
    hkeys[2*tid] = a; hkeys[2*tid+1] = b;
    tf2x32(0u, 7u, 0u, (unsigned)tid, a, b);
    lkeys[2*tid] = a; lkeys[2*tid+1] = b;
  }
  if (tid == 0) {
    float s = 0.f;
    for (int k = 0; k < 256; ++k) s += lvin[k];
    Lsum[0] = s;
  }
  {
    float a = 0.f, a2 = 0.f;
    for (int k = 0; k < 2*E_; ++k) {
      a  = fmaf(init_w[k],     Wv[(size_t)k*E_ + tid], a);
      a2 = fmaf(low_init_w[k], lWv[(size_t)k*E_ + tid], a2);
    }
    s_iwv[tid] = a; s_liwv[tid] = a2;
  }
  __syncthreads();
  {
    float a = 0.f, a2 = 0.f;
    for (int e = 0; e < E_; ++e) {
      a  = fmaf(s_iwv[e],  hWq[(size_t)e*H_ + tid], a);
      a2 = fmaf(s_liwv[e], lWq[(size_t)e*H_ + tid], a2);
    }
    g0h[tid] = a; g0l[tid] = a2;
  }
}

// ---------------- means over middle dim ----------------
__global__ __launch_bounds__(256) void k_mean(const float* __restrict__ in,
                                              float* __restrict__ out, int G) {
  int row = blockIdx.x, h = threadIdx.x;
  const float* p = in + (size_t)row * G * E_ + h;
  float a = 0.f;
  for (int g = 0; g < G; ++g) a += p[(size_t)g * E_];
  out[(size_t)row * E_ + h] = a * (1.0f / G);
}

// ---------------- generic small GEMM: C = (A .+ avec) @ W + bias ----------------
__global__ __launch_bounds__(256) void k_gemm(
    const float* __restrict__ A, int lda, const float* __restrict__ avec,
    const float* __restrict__ W, const float* __restrict__ bias,
    float* __restrict__ C, int M, int N, int K) {
  __shared__ float As[16][17];
  int i0 = blockIdx.x * 16, j0 = blockIdx.y * 64;
  int tx = threadIdx.x & 63, ty = threadIdx.x >> 6;
  int j = j0 + tx;
  float acc[4] = {0.f, 0.f, 0.f, 0.f};
  for (int kk = 0; kk < K; kk += 16) {
    int r = threadIdx.x >> 4, cc = threadIdx.x & 15;
    float av = A[(size_t)(i0 + r) * lda + kk + cc];
    if (avec) av += avec[kk + cc];
    As[r][cc] = av;
    __syncthreads();
#pragma unroll
    for (int kt = 0; kt < 16; ++kt) {
      float w = W[(size_t)(kk + kt) * N + j];
#pragma unroll
      for (int k2 = 0; k2 < 4; ++k2)
        acc[k2] = fmaf(As[ty*4 + k2][kt], w, acc[k2]);
    }
    __syncthreads();
  }
  float bb = bias ? bias[j] : 0.f;
#pragma unroll
  for (int k2 = 0; k2 < 4; ++k2)
    C[(size_t)(i0 + ty*4 + k2) * N + j] = acc[k2] + bb;
}

// ---------------- gathered GEMM: sbase[o] = hq0l[cell_o] + node_ctx[arow_o] @ M1l ----------------
__global__ __launch_bounds__(256) void k_gemmg(
    const float* __restrict__ nodectx, const int* __restrict__ arow,
    const int* __restrict__ cellarr, const float* __restrict__ W,
    const float* __restrict__ hq0l, float* __restrict__ C) {
  __shared__ float As[16][17];
  __shared__ int rows[16];
  int i0 = blockIdx.x * 16, j0 = blockIdx.y * 64;
  int tx = threadIdx.x & 63, ty = threadIdx.x >> 6;
  int j = j0 + tx;
  if (threadIdx.x < 16) rows[threadIdx.x] = arow[i0 + threadIdx.x];
  __syncthreads();
  float acc[4] = {0.f, 0.f, 0.f, 0.f};
  for (int kk = 0; kk < 256; kk += 16) {
    int r = threadIdx.x >> 4, cc = threadIdx.x & 15;
    As[r][cc] = nodectx[(size_t)rows[r] * 256 + kk + cc];
    __syncthreads();
#pragma unroll
    for (int kt = 0; kt < 16; ++kt) {
      float w = W[(size_t)(kk + kt) * 256 + j];
#pragma unroll
      for (int k2 = 0; k2 < 4; ++k2)
        acc[k2] = fmaf(As[ty*4 + k2][kt], w, acc[k2]);
    }
    __syncthreads();
  }
#pragma unroll
  for (int k2 = 0; k2 < 4; ++k2) {
    int row = i0 + ty*4 + k2;
    C[(size_t)row * 256 + j] = acc[k2] + hq0l[(size_t)cellarr[row] * 256 + j];
  }
}

// ---------------- big GEMM v6: [R|Q] = node_ctx(131072x256) @ [lWr | Al](256x512)
// Body = v3 EXACTLY (single-buffer, BK=16, bounds (256,2), 2-way Ws mapping —
// the 386 us verified best; VGPR 52). ONE isolated change: XCD-local temporal
// grid swizzle. Old grid (1024,4): variants of panel p at linear p+{0,1024,..}
// — same XCD (1024%8==0) but ~4 grid-waves apart, panel evicted from 4MB L2
// between uses (FETCH 313MB = A read 2.3x; drain stall = HBM 900cyc latency).
// New 1-D grid 4096: L -> bx=((L>>5)<<3)|(L&7), by=(L>>3)&3. Variants at
// L=(p>>3)*32+v*8+(p&7): same XCD (delta=8), within 32 blocks temporally ->
// A panel L2-hot for variants 1-3; drains hit L2 (~200cyc) not HBM.
// Pure index relabeling: outputs bitwise identical.
__global__ __launch_bounds__(256, 2) void k_bgemm(
    const float* __restrict__ A, const float* __restrict__ Wr,
    const float* __restrict__ Alm, const float* __restrict__ lbr,
    float* __restrict__ Rout, float* __restrict__ Qout) {
  __shared__ float As[16][132];
  __shared__ float Ws[16][132];
  int L = blockIdx.x;
  int bx = ((L >> 5) << 3) | (L & 7);   // panel 0..1023
  int by = (L >> 3) & 3;                // variant 0..3
  const float* Wbase = (by < 2) ? Wr : Alm;
  float* Cbase = (by < 2) ? Rout : Qout;
  int jb = (by & 1) * 128;
  bool doBias = (by < 2);
  int m0 = bx * 128;
  int tid = threadIdx.x;
  int tx = tid & 15, ty = tid >> 4;
  float acc[8][8];
#pragma unroll
  for (int i = 0; i < 8; ++i)
#pragma unroll
    for (int j = 0; j < 8; ++j) acc[i][j] = 0.f;

  for (int kc = 0; kc < 256; kc += 16) {
    {
      int kq = (tid & 3) * 4;
#pragma unroll
      for (int p = 0; p < 2; ++p) {
        int m = (tid >> 2) + p * 64;
        float4 a4 = *(const float4*)&A[(size_t)(m0 + m) * 256 + kc + kq];
        As[kq + 0][m] = a4.x; As[kq + 1][m] = a4.y;
        As[kq + 2][m] = a4.z; As[kq + 3][m] = a4.w;
      }
      int k = tid >> 4;
      int c4 = (tid & 15) * 8;
      float4 w0 = *(const float4*)&Wbase[(size_t)(kc + k) * 256 + jb + c4];
      float4 w1 = *(const float4*)&Wbase[(size_t)(kc + k) * 256 + jb + c4 + 4];
      *(float4*)&Ws[k][c4] = w0;
      *(float4*)&Ws[k][c4 + 4] = w1;
    }
    __syncthreads();
#pragma unroll
    for (int k = 0; k < 16; ++k) {
      float4 a0 = *(float4*)&As[k][ty * 8];
      float4 a1 = *(float4*)&As[k][ty * 8 + 4];
      float4 w0 = *(float4*)&Ws[k][tx * 4];        // cols jb+tx*4..+3   (2-way banks)
      float4 w1 = *(float4*)&Ws[k][tx * 4 + 64];   // cols jb+64+tx*4..+3
      float av[8] = {a0.x, a0.y, a0.z, a0.w, a1.x, a1.y, a1.z, a1.w};
      float wv[8] = {w0.x, w0.y, w0.z, w0.w, w1.x, w1.y, w1.z, w1.w};
#pragma unroll
      for (int i = 0; i < 8; ++i)
#pragma unroll
        for (int j = 0; j < 8; ++j)
          acc[i][j] = fmaf(av[i], wv[j], acc[i][j]);
    }
    __syncthreads();
  }
  float bias0[4], bias1[4];
#pragma unroll
  for (int j = 0; j < 4; ++j) {
    bias0[j] = doBias ? lbr[jb + tx * 4 + j] : 0.f;
    bias1[j] = doBias ? lbr[jb + 64 + tx * 4 + j] : 0.f;
  }
#pragma unroll
  for (int i = 0; i < 8; ++i) {
    float4 o0 = make_float4(acc[i][0] + bias0[0], acc[i][1] + bias0[1],
                            acc[i][2] + bias0[2], acc[i][3] + bias0[3]);
    float4 o1 = make_float4(acc[i][4] + bias1[0], acc[i][5] + bias1[1],
                            acc[i][6] + bias1[2], acc[i][7] + bias1[3]);
    size_t row = (size_t)(m0 + ty * 8 + i);
    *(float4*)&Cbase[row * 256 + jb + tx * 4] = o0;
    *(float4*)&Cbase[row * 256 + jb + 64 + tx * 4] = o1;
  }
}

// ---------------- u0 for all cells ----------------
__global__ __launch_bounds__(256) void k_u0k(
    const float* __restrict__ R, const float* __restrict__ hq0l,
    const float* __restrict__ g0l, const float* __restrict__ lv,
    float* __restrict__ u0) {
  int cell = blockIdx.x, tid = threadIdx.x, lane = tid & 63, w = tid >> 6;
  __shared__ float qs[256];
  qs[tid] = hq0l[(size_t)cell*256 + tid] + g0l[tid];
  __syncthreads();
  float lvr[4], qsr[4];
#pragma unroll
  for (int q = 0; q < 4; ++q) { lvr[q] = lv[lane + 64*q]; qsr[q] = qs[lane + 64*q]; }
  const float* Rb = R + (size_t)cell * 16384;
  for (int i = 0; i < 16; ++i) {
    int n = w*16 + i;
    const float* rr = Rb + (size_t)n*256;
    float a = 0.f;
#pragma unroll
    for (int q = 0; q < 4; ++q)
      a = fmaf(lvr[q], ftanh(qsr[q] + rr[lane + 64*q]), a);
#pragma unroll
    for (int off = 32; off; off >>= 1) a += __shfl_xor(a, off);
    if (lane == 0) u0[(size_t)cell*64 + n] = 10.0f * ftanh(a);
  }
}

// ---------------- phase A: high-level sampling chain ----------------
__global__ __launch_bounds__(256) void k_high(
    const float* __restrict__ cell_ctx, const int* __restrict__ high_mask,
    const float* __restrict__ hv,
    const float* __restrict__ ws_hq0h, const float* __restrict__ ws_g0h,
    const float* __restrict__ ws_Qh, const float* __restrict__ ws_rhigh,
    const float* __restrict__ ws_M1h, const unsigned* __restrict__ ws_hkeys,
    int* __restrict__ ws_hidx, float* __restrict__ ws_hlogp) {
  int b = blockIdx.x, tid = threadIdx.x;
  int lane = tid & 63, w = tid >> 6;
  __shared__ float s[H_], addM[H_], hq0[H_], g0[H_], hvv[H_];
  __shared__ float uarr[NC_];
  __shared__ int prev_s;
  __shared__ unsigned hm_s;
  __shared__ float acc_s;
  hq0[tid] = ws_hq0h[(size_t)b*H_ + tid];
  g0[tid] = ws_g0h[tid];
  hvv[tid] = hv[tid];
  if (tid == 0) {
    unsigned m = 0;
    for (int c = 0; c < NC_; ++c) if (high_mask[b*NC_ + c] > 0) m |= (1u << c);
    hm_s = m; acc_s = 0.f; prev_s = 0;
  }
  __syncthreads();
  for (int t = 0; t < NC_; ++t) {
    {
      float v = hq0[tid];
      if (t == 0) v += g0[tid];
      else        v += addM[tid] + ws_Qh[(size_t)(b*NC_ + prev_s)*H_ + tid];
      s[tid] = v;
    }
    __syncthreads();
    unsigned hm = hm_s;
    for (int q8 = 0; q8 < 8; ++q8) {
      int cidx = w*8 + q8;
      if ((hm >> cidx) & 1u) continue;
      const float* rr = ws_rhigh + (size_t)(b*NC_ + cidx)*H_;
      float a = 0.f;
#pragma unroll
      for (int jj = 0; jj < 4; ++jj) {
        int h = lane + 64*jj;
        a += hvv[h] * ftanh(s[h] + rr[h]);
      }
#pragma unroll
      for (int off = 32; off; off >>= 1) a += __shfl_xor(a, off);
      if (lane == 0) uarr[cidx] = 10.0f * ftanh(a);
    }
    __syncthreads();
    if (w == 0) {
      int cidx = lane;
      bool valid = (cidx < NC_);
      bool masked = valid && ((hm >> cidx) & 1u);
      float logit = valid ? (masked ? -1e9f : uarr[cidx]) : -INFINITY;
      float val = -INFINITY;
      if (valid) {
        float g = gumbel_bits(ws_hkeys[2*t], ws_hkeys[2*t+1],
                              (unsigned)(b*NC_ + cidx));
        val = logit + g;
      }
      float bvv = val; int bi = valid ? cidx : 9999;
#pragma unroll
      for (int off = 32; off; off >>= 1) {
        float ov = __shfl_xor(bvv, off); int oi = __shfl_xor(bi, off);
        if (ov > bvv || (ov == bvv && oi < bi)) { bvv = ov; bi = oi; }
      }
      float m = logit;
#pragma unroll
      for (int off = 32; off; off >>= 1) m = fmaxf(m, __shfl_xor(m, off));
      float ex = (valid && !masked) ? expf(logit - m) : 0.f;
#pragma unroll
      for (int off = 32; off; off >>= 1) ex += __shfl_xor(ex, off);
      float lsel = __shfl(logit, bi);
      float logp = lsel - m - logf(ex);
      if (lane == 0) {
        acc_s += logp;
        ws_hidx[b*NC_ + t] = bi;
        hm_s = hm | (1u << bi);
        prev_s = bi;
      }
    }
    __syncthreads();
    if (t == 0) {
      {
        int idx0 = prev_s;
        const float* crow = cell_ctx + (size_t)(b*NC_ + idx0)*E_;
        float a = 0.f;
        for (int e = 0; e < E_; ++e)
          a = fmaf(crow[e], ws_M1h[(size_t)e*H_ + tid], a);
        addM[tid] = a;
      }
      __syncthreads();
    }
  }
  if (tid == 0) ws_hlogp[b] = acc_s;
}

// ---------------- idx0 sampling (step 0) per (b,t) ----------------
__global__ __launch_bounds__(256) void k_idx0(
    const int* __restrict__ low_mask, const unsigned* __restrict__ lkeys,
    const int* __restrict__ hidx, const float* __restrict__ u0,
    int* __restrict__ arow, int* __restrict__ cellarr) {
  int tid = threadIdx.x, lane = tid & 63, w = tid >> 6;
  int o = blockIdx.x * 4 + w;
  int b = o >> 5, t = o & 31;
  int c = hidx[o], cell = b*NC_ + c;
  float logit = (low_mask[(size_t)cell*64 + lane] > 0) ? -1e9f
               : u0[(size_t)cell*64 + lane];
  unsigned s0, s1;
  tf2x32(lkeys[2*t], lkeys[2*t+1], 0u, 0u, s0, s1);
  float g = gumbel_bits(s0, s1, (unsigned)(b*NL_ + lane));
  float val = logit + g;
  float bvv = val; int bi = lane;
#pragma unroll
  for (int off = 32; off; off >>= 1) {
    float ov = __shfl_xor(bvv, off); int oi = __shfl_xor(bi, off);
    if (ov > bvv || (ov == bvv && oi < bi)) { bvv = ov; bi = oi; }
  }
  if (lane == 0) { arow[o] = cell*64 + bi; cellarr[o] = cell; }
}

// ---------------- U table v4: separable exp ----------------
// Key identity: exp(2(q+r)) = exp(2q)*exp(2r). Stage Er = exp(2R) into r_lds
// (16K exps/block) and Eq = exp(2(sb+Q)) into qrow (32K exps/block) instead of
// applying exp per (j,n,h) element (1.05M exps/block). Inner element:
//   acc = fma(lv, rcp(fma(Eq, Er, 1.0)), acc)
#define S_LDS 260
#define QPAD  264
__global__ __launch_bounds__(512, 6) void k_utab(
    const float* __restrict__ R, const float* __restrict__ Qm,
    const float* __restrict__ sbase, const float* __restrict__ lv,
    const float* __restrict__ Lsum, const int* __restrict__ hidx,
    float* __restrict__ U) {
  __shared__ float r_lds[32 * S_LDS];     // 32 rows of exp(2*r)  (33.3 KB)
  __shared__ float qrow[8][2 * QPAD];     // per-wave exp(2*(sbase+Q[j0/j1])) (16.9 KB)
  __shared__ float lvs[256];
  int tid = threadIdx.x, lane = tid & 63, w = tid >> 6;
  int o = blockIdx.x;
  int c = hidx[o], cell = (o >> 5) * NC_ + c;
  const float* Rb = R + (size_t)cell * 16384;
  const float* Qb = Qm + (size_t)cell * 16384;
  if (tid < 64) *(float4*)&lvs[4*tid] = *(const float4*)&lv[4*tid];
  float Ls = Lsum[0];
  float4 sb4 = *(const float4*)&sbase[(size_t)o*256 + 4*lane];
  int rbase = (lane >> 5) * 128;   // h-half this lane covers
  int nloc = lane & 31;            // local row index (conflict-free: measured r3)
  float* qw = qrow[w];
  for (int p = 0; p < 2; ++p) {
    if (p) __syncthreads();
    // stage rows p*32..+31 as exp(2*r), fully coalesced
#pragma unroll
    for (int k = 0; k < 4; ++k) {
      int f = tid + 512*k;
      int nl = f >> 6, h4 = (f & 63) * 4;
      float4 v = *(const float4*)&Rb[(size_t)(p*32 + nl)*256 + h4];
      *(float4*)&r_lds[nl*S_LDS + h4] =
          make_float4(__expf(v.x + v.x), __expf(v.y + v.y),
                      __expf(v.z + v.z), __expf(v.w + v.w));
    }
    __syncthreads();
    for (int jj = 0; jj < 4; ++jj) {
      int j0 = w*8 + 2*jj;
      {
        float4 qa = *(const float4*)&Qb[(size_t)j0*256 + 4*lane];
        float4 qb = *(const float4*)&Qb[(size_t)(j0+1)*256 + 4*lane];
        *(float4*)&qw[4*lane] =
            make_float4(__expf(2.f*(sb4.x + qa.x)), __expf(2.f*(sb4.y + qa.y)),
                        __expf(2.f*(sb4.z + qa.z)), __expf(2.f*(sb4.w + qa.w)));
        *(float4*)&qw[QPAD + 4*lane] =
            make_float4(__expf(2.f*(sb4.x + qb.x)), __expf(2.f*(sb4.y + qb.y)),
                        __expf(2.f*(sb4.z + qb.z)), __expf(2.f*(sb4.w + qb.w)));
      }
      // in-wave LDS RAW on qw: per-wave DS ordering (r3-proven pattern)
      float4 acc0 = make_float4(0.f, 0.f, 0.f, 0.f);
      float4 acc1 = make_float4(0.f, 0.f, 0.f, 0.f);
#pragma unroll 8
      for (int cc = 0; cc < 32; ++cc) {
        int hh = rbase + 4*cc;
        float4 rv = *(float4*)&r_lds[nloc*S_LDS + hh];   // Er
        float4 l4 = *(float4*)&lvs[hh];
        float4 q0 = *(float4*)&qw[hh];                   // Eq (j0)
        float4 q1 = *(float4*)&qw[QPAD + hh];            // Eq (j0+1)
        acc0.x = fmaf(l4.x, __builtin_amdgcn_rcpf(fmaf(q0.x, rv.x, 1.f)), acc0.x);
        acc0.y = fmaf(l4.y, __builtin_amdgcn_rcpf(fmaf(q0.y, rv.y, 1.f)), acc0.y);
        acc0.z = fmaf(l4.z, __builtin_amdgcn_rcpf(fmaf(q0.z, rv.z, 1.f)), acc0.z);
        acc0.w = fmaf(l4.w, __builtin_amdgcn_rcpf(fmaf(q0.w, rv.w, 1.f)), acc0.w);
        acc1.x = fmaf(l4.x, __builtin_amdgcn_rcpf(fmaf(q1.x, rv.x, 1.f)), acc1.x);
        acc1.y = fmaf(l4.y, __builtin_amdgcn_rcpf(fmaf(q1.y, rv.y, 1.f)), acc1.y);
        acc1.z = fmaf(l4.z, __builtin_amdgcn_rcpf(fmaf(q1.z, rv.z, 1.f)), acc1.z);
        acc1.w = fmaf(l4.w, __builtin_amdgcn_rcpf(fmaf(q1.w, rv.w, 1.f)), acc1.w);
      }
      // u = 10*tanh(L - 2*S) where S = sum lv*sigma(-2z)
      float a0 = (acc0.x + acc0.y) + (acc0.z + acc0.w);
      float a1 = (acc1.x + acc1.y) + (acc1.z + acc1.w);
      a0 += __shfl_xor(a0, 32);
      a1 += __shfl_xor(a1, 32);
      if (lane < 32) {
        float* Uo = U + (size_t)o*4096 + j0*64 + p*32 + lane;
        Uo[0]  = 10.0f * ftanh(fmaf(-2.f, a0, Ls));
        Uo[64] = 10.0f * ftanh(fmaf(-2.f, a1, Ls));
      }
    }
  }
}

// ---------------- sequential low sampler: one wave per (b,t) ----------------
__global__ __launch_bounds__(256) void k_lowseq(
    const float* __restrict__ orig, const int* __restrict__ low_mask,
    const unsigned* __restrict__ lkeys, const int* __restrict__ hidx,
    const float* __restrict__ u0, const float* __restrict__ U,
    float* __restrict__ llogp, float* __restrict__ lRr,
    float* __restrict__ lastn, float* __restrict__ initn) {
  int tid = threadIdx.x, lane = tid & 63, w = tid >> 6;
  int o = blockIdx.x * 4 + w;
  int b = o >> 5, t = o & 31;
  int c = hidx[o], cell = b*NC_ + c;
  float cx = orig[(size_t)cell*128 + 2*lane];
  float cy = orig[(size_t)cell*128 + 2*lane + 1];
  int maskb = (low_mask[(size_t)cell*64 + lane] > 0) ? 1 : 0;
  unsigned sk0, sk1;
  tf2x32(lkeys[2*t], lkeys[2*t+1], 0u, (unsigned)lane, sk0, sk1);
  float row = u0[(size_t)cell*64 + lane];
  float px = __shfl(cx, 0), py = __shfl(cy, 0);
  float ix = px, iy = py;
  float lp = 0.f, rw = 0.f;
  const float* Ub = U + (size_t)o * 4096;
  for (int s = 0; s < NL_; ++s) {
    float logit = maskb ? -1e9f : row;
    unsigned k0 = (unsigned)__shfl((int)sk0, s);
    unsigned k1 = (unsigned)__shfl((int)sk1, s);
    float g = gumbel_bits(k0, k1, (unsigned)(b*NL_ + lane));
    float val = logit + g;
    float bvv = val; int bi = lane;
#pragma unroll
    for (int off = 32; off; off >>= 1) {
      float ov = __shfl_xor(bvv, off); int oi = __shfl_xor(bi, off);
      if (ov > bvv || (ov == bvv && oi < bi)) { bvv = ov; bi = oi; }
    }
    float nrow = Ub[(size_t)bi*64 + lane];
    float m = logit;
#pragma unroll
    for (int off = 32; off; off >>= 1) m = fmaxf(m, __shfl_xor(m, off));
    float ex = maskb ? 0.f : expf(logit - m);
#pragma unroll
    for (int off = 32; off; off >>= 1) ex += __shfl_xor(ex, off);
    float lsel = __shfl(logit, bi);
    lp += lsel - m - logf(ex);
    float bx = __shfl(cx, bi), by = __shfl(cy, bi);
    float dx = bx - px, dy = by - py;
    rw += sqrtf(dx*dx + dy*dy + 1e-12f);
    px = bx; py = by;
    if (lane == bi) maskb = 1;
    row = nrow;
  }
  if (lane == 0) {
    llogp[o] = lp; lRr[o] = rw;
    lastn[2*o] = px; lastn[2*o+1] = py;
    initn[2*o] = ix; initn[2*o+1] = iy;
  }
}

// ---------------- phase C: stitch ----------------
__global__ __launch_bounds__(64) void k_stitch(
    const float* __restrict__ ws_hlogp, const float* __restrict__ ws_llogp,
    const float* __restrict__ ws_lR, const float* __restrict__ ws_lastn,
    const float* __restrict__ ws_initn, float* __restrict__ out) {
  int b = threadIdx.x;
  if (b >= B_) return;
  float lp = ws_hlogp[b], rw = 0.f, lx = 0.f, ly = 0.f;
  for (int t = 0; t < NC_; ++t) {
    int o = b*NC_ + t;
    lp += ws_llogp[o];
    float dx = ws_initn[2*o] - lx, dy = ws_initn[2*o+1] - ly;
    rw += ws_lR[o] + sqrtf(dx*dx + dy*dy + 1e-12f);
    lx = ws_lastn[2*o]; ly = ws_lastn[2*o+1];
  }
  out[b] = lp;
  out[B_ + b] = rw;
}

// ---------------- host launcher ----------------
extern "C" void kernel_launch(void* const* d_in, const int* in_sizes, int n_in,
                              void* d_out, int out_size, void* d_ws, size_t ws_size,
                              hipStream_t stream) {
  const float* node_ctx  = (const float*)d_in[0];
  const float* cell_ctx  = (const float*)d_in[1];
  const float* orig      = (const float*)d_in[2];
  const int*   high_mask = (const int*)d_in[3];
  const int*   low_mask  = (const int*)d_in[4];
  const float* init_w    = (const float*)d_in[5];
  const float* Wc        = (const float*)d_in[6];
  const float* bc        = (const float*)d_in[7];
  const float* Wv        = (const float*)d_in[8];
  const float* bv        = (const float*)d_in[9];
  const float* hWq       = (const float*)d_in[10];
  const float* hbq       = (const float*)d_in[11];
  const float* hWr       = (const float*)d_in[12];
  const float* hbr       = (const float*)d_in[13];
  const float* hv        = (const float*)d_in[14];
  const float* low_init_w= (const float*)d_in[15];
  const float* lWc       = (const float*)d_in[16];
  const float* lbc       = (const float*)d_in[17];
  const float* lWv       = (const float*)d_in[18];
  const float* lbv       = (const float*)d_in[19];
  const float* lWq       = (const float*)d_in[20];
  const float* lbq       = (const float*)d_in[21];
  const float* lWr       = (const float*)d_in[22];
  const float* lbr       = (const float*)d_in[23];
  const float* lv        = (const float*)d_in[24];
  float* out = (float*)d_out;

  char* ws = (char*)d_ws;
  size_t off = 0;
  auto alloc = [&](size_t bytes) -> void* {
    void* p = ws + off;
    off += (bytes + 255) & ~(size_t)255;
    return p;
  };
  unsigned* w_hkeys = (unsigned*)alloc(32*2*4);
  unsigned* w_lkeys = (unsigned*)alloc(32*2*4);
  int*   w_hidx  = (int*)alloc(2048*4);
  int*   w_arow  = (int*)alloc(2048*4);
  int*   w_cell  = (int*)alloc(2048*4);
  float* w_hlogp = (float*)alloc(64*4);
  float* w_llogp = (float*)alloc(2048*4);
  float* w_lR    = (float*)alloc(2048*4);
  float* w_lastn = (float*)alloc(2048*2*4);
  float* w_initn = (float*)alloc(2048*2*4);
  float* w_g0h   = (float*)alloc(256*4);
  float* w_g0l   = (float*)alloc(256*4);
  float* w_Lsum  = (float*)alloc(4);
  float* w_M1h   = (float*)alloc((size_t)65536*4);
  float* w_Ah    = (float*)alloc((size_t)65536*4);
  float* w_M1l   = (float*)alloc((size_t)65536*4);
  float* w_Al    = (float*)alloc((size_t)65536*4);
  float* w_mcc   = (float*)alloc((size_t)64*256*4);
  float* w_mnc   = (float*)alloc((size_t)2048*256*4);
  float* w_hbh   = (float*)alloc((size_t)64*256*4);
  float* w_hq0h  = (float*)alloc((size_t)64*256*4);
  float* w_rhigh = (float*)alloc((size_t)2048*256*4);
  float* w_Qh    = (float*)alloc((size_t)2048*256*4);
  float* w_hbl   = (float*)alloc((size_t)2048*256*4);
  float* w_hq0l  = (float*)alloc((size_t)2048*256*4);
  float* w_u0    = (float*)alloc((size_t)2048*64*4);
  float* w_sbase = (float*)alloc((size_t)2048*256*4);
  float* w_U     = (float*)alloc((size_t)2048*4096*4);
  float* w_R     = (float*)alloc((size_t)2048*64*256*4);
  float* w_Qm    = (float*)alloc((size_t)2048*64*256*4);
  (void)ws_size; (void)in_sizes; (void)n_in; (void)out_size;

  k0_kernel<<<1, 256, 0, stream>>>(init_w, Wv, hWq, low_init_w, lWv, lWq, lv,
                                   w_hkeys, w_lkeys, w_g0h, w_g0l, w_Lsum);
  k_mean<<<2048, 256, 0, stream>>>(node_ctx, w_mnc, 64);
  k_mean<<<64, 256, 0, stream>>>(cell_ctx, w_mcc, 32);

  dim3 g256(16, 4), g2048(128, 4), g64(4, 4);
  k_gemm<<<g256, 256, 0, stream>>>(Wv,            256, nullptr, hWq, nullptr, w_M1h, 256, 256, 256);
  k_gemm<<<g256, 256, 0, stream>>>(Wv + 65536,    256, nullptr, hWq, nullptr, w_Ah,  256, 256, 256);
  k_gemm<<<g256, 256, 0, stream>>>(lWv,           256, nullptr, lWq, nullptr, w_M1l, 256, 256, 256);
  k_gemm<<<g256, 256, 0, stream>>>(lWv + 65536,   256, nullptr, lWq, nullptr, w_Al,  256, 256, 256);
  k_gemm<<<g2048, 256, 0, stream>>>(cell_ctx, 256, nullptr, hWr, hbr, w_rhigh, 2048, 256, 256);
  k_gemm<<<g2048, 256, 0, stream>>>(cell_ctx, 256, nullptr, w_Ah, nullptr, w_Qh, 2048, 256, 256);
  k_gemm<<<g64,   256, 0, stream>>>(w_mcc, 256, nullptr, Wc,  bc,  w_hbh, 64,   256, 256);
  k_gemm<<<g2048, 256, 0, stream>>>(w_mnc, 256, nullptr, lWc, lbc, w_hbl, 2048, 256, 256);
  k_gemm<<<g64,   256, 0, stream>>>(w_hbh, 256, bv,  hWq, hbq, w_hq0h, 64,   256, 256);
  k_gemm<<<g2048, 256, 0, stream>>>(w_hbl, 256, lbv, lWq, lbq, w_hq0l, 2048, 256, 256);

  k_bgemm<<<4096, 256, 0, stream>>>(node_ctx, lWr, w_Al, lbr, w_R, w_Qm);
  k_u0k<<<2048, 256, 0, stream>>>(w_R, w_hq0l, w_g0l, lv, w_u0);

  k_high<<<64, 256, 0, stream>>>(cell_ctx, high_mask, hv, w_hq0h, w_g0h, w_Qh,
                                 w_rhigh, w_M1h, w_hkeys, w_hidx, w_hlogp);
  k_idx0<<<512, 256, 0, stream>>>(low_mask, w_lkeys, w_hidx, w_u0, w_arow, w_cell);
  k_gemmg<<<dim3(128, 4), 256, 0, stream>>>(node_ctx, w_arow, w_cell, w_M1l,
                                            w_hq0l, w_sbase);
  k_utab<<<2048, 512, 0, stream>>>(w_R, w_Qm, w_sbase, lv, w_Lsum, w_hidx, w_U);
  k_lowseq<<<512, 256, 0, stream>>>(orig, low_mask, w_lkeys, w_hidx, w_u0, w_U,
                                    w_llogp, w_lR, w_lastn, w_initn);
  k_stitch<<<1, 64, 0, stream>>>(w_hlogp, w_llogp, w_lR, w_lastn, w_initn, out);
}